// Round 1
// 1233.293 us; speedup vs baseline: 4.6201x; 4.6201x over previous
//
#include <hip/hip_runtime.h>
#include <math.h>

#define TT   2048   // tokens
#define HH   2048   // hidden
#define IE   512    // expert inter
#define SIE  1024   // shared inter
#define NE   64     // experts
#define TOPK 8

#define TS   128    // expert M tile (pairs)
#define NC   128    // expert N chunk
#define TSS  64     // shared M tile
#define NCS  64     // shared N chunk
#define KB   32     // K block
#define KS   40     // LDS k-stride in bf16 elems (32 + 8 pad, 80 B)

typedef __attribute__((ext_vector_type(8))) short short8;
typedef __attribute__((ext_vector_type(4))) float f32x4;

__device__ __forceinline__ unsigned short f2bf(float f) {
  unsigned int u = __float_as_uint(f);
  u += 0x7FFF + ((u >> 16) & 1);   // RNE
  return (unsigned short)(u >> 16);
}

// ---------------------------------------------------------------- router
__global__ __launch_bounds__(256) void k_router(
    const float* __restrict__ x, const float* __restrict__ rw,
    int* __restrict__ cnt, int* __restrict__ list, float* __restrict__ wtb)
{
  __shared__ float rwS[64 * 65];
  __shared__ float xs[8 * 68];
  const int tid  = threadIdx.x;
  const int lane = tid & 63;       // = expert index
  const int g    = tid >> 6;       // wave id, owns tokens g*2, g*2+1
  const int t0   = blockIdx.x * 8;

  float part0 = 0.f, part1 = 0.f;
  for (int h0 = 0; h0 < HH; h0 += 64) {
    {
      const int e = tid >> 2, c = (tid & 3) * 16;
      const float* src = rw + (size_t)e * HH + h0 + c;
      #pragma unroll
      for (int u = 0; u < 4; ++u) {
        float4 v = *(const float4*)(src + u * 4);
        float* dst = &rwS[e * 65 + c + u * 4];
        dst[0] = v.x; dst[1] = v.y; dst[2] = v.z; dst[3] = v.w;
      }
    }
    if (tid < 128) {
      const int tl = tid >> 4, c = (tid & 15) * 4;
      *(float4*)&xs[tl * 68 + c] =
          *(const float4*)(x + (size_t)(t0 + tl) * HH + h0 + c);
    }
    __syncthreads();
    const float* rrow = &rwS[lane * 65];
    const float* x0 = &xs[(g * 2 + 0) * 68];
    const float* x1 = &xs[(g * 2 + 1) * 68];
    #pragma unroll 8
    for (int j = 0; j < 64; ++j) {
      float rv = rrow[j];
      part0 = fmaf(x0[j], rv, part0);
      part1 = fmaf(x1[j], rv, part1);
    }
    __syncthreads();
  }

  for (int it = 0; it < 2; ++it) {
    const int t = t0 + g * 2 + it;
    float v = (it == 0) ? part0 : part1;
    float m = v;
    #pragma unroll
    for (int off = 32; off; off >>= 1) m = fmaxf(m, __shfl_xor(m, off));
    float p = expf(v - m);
    float s = p;
    #pragma unroll
    for (int off = 32; off; off >>= 1) s += __shfl_xor(s, off);
    p /= s;

    float pv = p, wsum = 0.f, myw = 0.f;
    int mye = 0;
    #pragma unroll
    for (int k = 0; k < TOPK; ++k) {
      float bv = pv; int bl = lane;
      #pragma unroll
      for (int off = 32; off; off >>= 1) {
        float ov = __shfl_xor(bv, off);
        int   ol = __shfl_xor(bl, off);
        if (ov > bv || (ov == bv && ol < bl)) { bv = ov; bl = ol; }
      }
      wsum += bv;
      if (lane == k)  { myw = bv; mye = bl; }
      if (lane == bl) pv = -1.f;
    }
    if (lane < TOPK) {
      wtb[t * TOPK + lane] = myw / wsum;
      int pos = atomicAdd(&cnt[mye], 1);
      list[mye * TT + pos] = t * TOPK + lane;   // pair id = t*8 + slot
    }
  }
}

// ------------------------------------------------------- expert gate/up
// grid 4096 = 8(xcd) x 8(e_hi) x 16(mt) x 4(nc); same-expert tiles share an XCD.
// 512 thr / 8 waves; nc split across blocks; B prefetched in regs across MFMA;
// LDS granule-XOR swizzle (write 16->8-way conflicts, reads conflict-free).
__global__ __launch_bounds__(512, 4) void k_gateup(
    const float* __restrict__ x, const float* __restrict__ wg, const float* __restrict__ wu,
    const int* __restrict__ cnt, const int* __restrict__ list, const float* __restrict__ wtb,
    unsigned short* __restrict__ P)
{
  const int b  = blockIdx.x;
  const int r  = b >> 3;
  const int e  = ((r & 7) << 3) | (b & 7);
  const int t  = r >> 3;          // 0..63
  const int mt = t >> 2;          // 0..15
  const int nc = t & 3;           // 0..3
  const int ne = cnt[e];
  const int m0 = mt * TS;
  if (m0 >= ne) return;

  __shared__ __align__(16) unsigned short As[TS * KS];
  __shared__ __align__(16) unsigned short Bg[NC * KS];
  __shared__ __align__(16) unsigned short Bu[NC * KS];
  __shared__ int   s_pair[TS];
  __shared__ int   s_tok[TS];
  __shared__ float s_w[TS];

  const int tid = threadIdx.x;
  if (tid < TS) {
    int idx = m0 + tid;
    int cl  = idx < ne ? idx : (ne - 1);
    int pr  = list[e * TT + cl];
    s_pair[tid] = pr;
    s_tok[tid]  = pr >> 3;
    s_w[tid]    = wtb[pr];
  }
  __syncthreads();

  const int lane = tid & 63, wv = tid >> 6, lm = lane & 15, lq = lane >> 4;
  const int x3 = (lq ^ ((lm >> 2) & 3)) << 3;          // swizzled read granule
  const int ar = tid >> 2, ag = tid & 3;
  const int n0 = nc * NC;

  const float* pa = x + (size_t)s_tok[ar] * HH + ag * 8;
  unsigned short* aw = &As[ar * KS + ((ag ^ ((ar >> 2) & 3)) << 3)];

  const int f40 = tid, f41 = 512 + tid;
  const int kl0 = f40 >> 5, n40 = (f40 & 31) * 4;
  const int kl1 = f41 >> 5, n41 = (f41 & 31) * 4;
  const int of0 = (((kl0 >> 3) ^ (f40 & 3)) << 3) | (kl0 & 7);
  const int of1 = (((kl1 >> 3) ^ (f41 & 3)) << 3) | (kl1 & 7);
  const size_t wbase = (size_t)e * HH * IE;
  const float* pg0 = wg + wbase + (size_t)kl0 * IE + n0 + n40;
  const float* pg1 = wg + wbase + (size_t)kl1 * IE + n0 + n41;
  const float* pu0 = wu + wbase + (size_t)kl0 * IE + n0 + n40;
  const float* pu1 = wu + wbase + (size_t)kl1 * IE + n0 + n41;

  const unsigned short* afr = &As[(wv * 16 + lm) * KS + x3];
  const unsigned short* bgr = &Bg[lm * KS + x3];
  const unsigned short* bur = &Bu[lm * KS + x3];

  const f32x4 zero = {0.f, 0.f, 0.f, 0.f};
  f32x4 accg[8], accu[8];
  #pragma unroll
  for (int j = 0; j < 8; ++j) { accg[j] = zero; accu[j] = zero; }

  // prologue: prefetch B k-block 0 into regs
  float4 vg0 = *(const float4*)pg0, vg1 = *(const float4*)pg1;
  float4 vu0 = *(const float4*)pu0, vu1 = *(const float4*)pu1;

  for (int kb = 0; kb < HH / KB; ++kb) {
    // issue A load early (L2-hot x rows); B writes below hide its latency
    const float4 va0 = *(const float4*)(pa + (size_t)kb * KB);
    const float4 va1 = *(const float4*)(pa + (size_t)kb * KB + 4);
    Bg[(n40+0)*KS+of0]=f2bf(vg0.x); Bg[(n40+1)*KS+of0]=f2bf(vg0.y);
    Bg[(n40+2)*KS+of0]=f2bf(vg0.z); Bg[(n40+3)*KS+of0]=f2bf(vg0.w);
    Bg[(n41+0)*KS+of1]=f2bf(vg1.x); Bg[(n41+1)*KS+of1]=f2bf(vg1.y);
    Bg[(n41+2)*KS+of1]=f2bf(vg1.z); Bg[(n41+3)*KS+of1]=f2bf(vg1.w);
    Bu[(n40+0)*KS+of0]=f2bf(vu0.x); Bu[(n40+1)*KS+of0]=f2bf(vu0.y);
    Bu[(n40+2)*KS+of0]=f2bf(vu0.z); Bu[(n40+3)*KS+of0]=f2bf(vu0.w);
    Bu[(n41+0)*KS+of1]=f2bf(vu1.x); Bu[(n41+1)*KS+of1]=f2bf(vu1.y);
    Bu[(n41+2)*KS+of1]=f2bf(vu1.z); Bu[(n41+3)*KS+of1]=f2bf(vu1.w);
    {
      short8 tv;
      tv[0]=f2bf(va0.x); tv[1]=f2bf(va0.y); tv[2]=f2bf(va0.z); tv[3]=f2bf(va0.w);
      tv[4]=f2bf(va1.x); tv[5]=f2bf(va1.y); tv[6]=f2bf(va1.z); tv[7]=f2bf(va1.w);
      *(short8*)aw = tv;
    }
    __syncthreads();
    if (kb + 1 < HH / KB) {   // prefetch next B; stays in flight through MFMA
      const size_t k1 = (size_t)(kb + 1) * KB;
      vg0 = *(const float4*)(pg0 + k1 * IE);
      vg1 = *(const float4*)(pg1 + k1 * IE);
      vu0 = *(const float4*)(pu0 + k1 * IE);
      vu1 = *(const float4*)(pu1 + k1 * IE);
    }
    short8 a = *(const short8*)afr;
    #pragma unroll
    for (int nt = 0; nt < 8; ++nt) {
      short8 bg = *(const short8*)(bgr + nt * 16 * KS);
      short8 bu = *(const short8*)(bur + nt * 16 * KS);
      accg[nt] = __builtin_amdgcn_mfma_f32_16x16x32_bf16(a, bg, accg[nt], 0, 0, 0);
      accu[nt] = __builtin_amdgcn_mfma_f32_16x16x32_bf16(a, bu, accu[nt], 0, 0, 0);
    }
    __syncthreads();
  }

  #pragma unroll
  for (int nt = 0; nt < 8; ++nt)
    #pragma unroll
    for (int r4 = 0; r4 < 4; ++r4) {
      int row = wv * 16 + lq * 4 + r4;
      if (m0 + row < ne) {
        float gg = accg[nt][r4];
        float uu = accu[nt][r4];
        float sv = gg / (1.f + expf(-gg)) * uu * s_w[row];
        P[(size_t)s_pair[row] * IE + n0 + nt * 16 + lm] = f2bf(sv);
      }
    }
}

// --------------------------------------------------------- expert down
// grid 16384 = 8(xcd) x 8(e_hi) x 16(mt) x 16(nc)
__global__ __launch_bounds__(512, 4) void k_down(
    const unsigned short* __restrict__ P, const float* __restrict__ wd,
    const int* __restrict__ cnt, const int* __restrict__ list,
    float* __restrict__ out)
{
  const int b  = blockIdx.x;
  const int r  = b >> 3;
  const int e  = ((r & 7) << 3) | (b & 7);
  const int t  = r >> 3;          // 0..255
  const int mt = t >> 4;          // 0..15
  const int nc = t & 15;          // 0..15
  const int ne = cnt[e];
  const int m0 = mt * TS;
  if (m0 >= ne) return;

  __shared__ __align__(16) unsigned short As[TS * KS];
  __shared__ __align__(16) unsigned short Bt[NC * KS];
  __shared__ int s_pair[TS];
  __shared__ int s_tok[TS];

  const int tid = threadIdx.x;
  if (tid < TS) {
    int idx = m0 + tid;
    int cl  = idx < ne ? idx : (ne - 1);
    int pr  = list[e * TT + cl];
    s_pair[tid] = pr;
    s_tok[tid]  = pr >> 3;
  }
  __syncthreads();

  const int lane = tid & 63, wv = tid >> 6, lm = lane & 15, lq = lane >> 4;
  const int x3 = (lq ^ ((lm >> 2) & 3)) << 3;
  const int ar = tid >> 2, ag = tid & 3;
  const int n0 = nc * NC;

  const unsigned short* pp = P + (size_t)s_pair[ar] * IE + ag * 8;
  unsigned short* aw = &As[ar * KS + ((ag ^ ((ar >> 2) & 3)) << 3)];

  const int f40 = tid, f41 = 512 + tid;
  const int kl0 = f40 >> 5, n40 = (f40 & 31) * 4;
  const int kl1 = f41 >> 5, n41 = (f41 & 31) * 4;
  const int of0 = (((kl0 >> 3) ^ (f40 & 3)) << 3) | (kl0 & 7);
  const int of1 = (((kl1 >> 3) ^ (f41 & 3)) << 3) | (kl1 & 7);
  const size_t wbase = (size_t)e * IE * HH;
  const float* pb0 = wd + wbase + (size_t)kl0 * HH + n0 + n40;
  const float* pb1 = wd + wbase + (size_t)kl1 * HH + n0 + n41;

  const unsigned short* afr = &As[(wv * 16 + lm) * KS + x3];
  const unsigned short* btr = &Bt[lm * KS + x3];

  const f32x4 zero = {0.f, 0.f, 0.f, 0.f};
  f32x4 acc[8];
  #pragma unroll
  for (int j = 0; j < 8; ++j) acc[j] = zero;

  float4 vb0 = *(const float4*)pb0, vb1 = *(const float4*)pb1;

  for (int kb = 0; kb < IE / KB; ++kb) {
    short8 sa = *(const short8*)(pp + (size_t)kb * KB);   // bf16 A copy
    Bt[(n40+0)*KS+of0]=f2bf(vb0.x); Bt[(n40+1)*KS+of0]=f2bf(vb0.y);
    Bt[(n40+2)*KS+of0]=f2bf(vb0.z); Bt[(n40+3)*KS+of0]=f2bf(vb0.w);
    Bt[(n41+0)*KS+of1]=f2bf(vb1.x); Bt[(n41+1)*KS+of1]=f2bf(vb1.y);
    Bt[(n41+2)*KS+of1]=f2bf(vb1.z); Bt[(n41+3)*KS+of1]=f2bf(vb1.w);
    *(short8*)aw = sa;
    __syncthreads();
    if (kb + 1 < IE / KB) {
      const size_t k1 = (size_t)(kb + 1) * KB;
      vb0 = *(const float4*)(pb0 + k1 * HH);
      vb1 = *(const float4*)(pb1 + k1 * HH);
    }
    short8 a = *(const short8*)afr;
    #pragma unroll
    for (int nt = 0; nt < 8; ++nt) {
      short8 bb = *(const short8*)(btr + nt * 16 * KS);
      acc[nt] = __builtin_amdgcn_mfma_f32_16x16x32_bf16(a, bb, acc[nt], 0, 0, 0);
    }
    __syncthreads();
  }

  #pragma unroll
  for (int nt = 0; nt < 8; ++nt)
    #pragma unroll
    for (int r4 = 0; r4 < 4; ++r4) {
      int row = wv * 16 + lq * 4 + r4;
      if (m0 + row < ne)
        atomicAdd(&out[(size_t)s_tok[row] * HH + n0 + nt * 16 + lm],
                  acc[nt][r4]);
    }
}

// ------------------------------------------------------ shared gate/up
// grid 512 = 32(mt) x 16(nc of 64)
__global__ __launch_bounds__(256) void k_sgateup(
    const float* __restrict__ x, const float* __restrict__ sg, const float* __restrict__ su,
    unsigned short* __restrict__ Ps)
{
  const int mt = blockIdx.x >> 4;   // 0..31
  const int nc = blockIdx.x & 15;   // 0..15
  const int m0 = mt * TSS, n0 = nc * NCS;

  __shared__ __align__(16) unsigned short As[TSS * KS];
  __shared__ __align__(16) unsigned short Bg[NCS * KS];
  __shared__ __align__(16) unsigned short Bu[NCS * KS];

  const int tid = threadIdx.x;
  const int lane = tid & 63, wv = tid >> 6, lm = lane & 15, lq = lane >> 4;
  const int x3 = (lq ^ ((lm >> 2) & 3)) << 3;
  const int ar = tid >> 2, ag = tid & 3;

  const float* pa = x + (size_t)(m0 + ar) * HH + ag * 8;
  unsigned short* aw = &As[ar * KS + ((ag ^ ((ar >> 2) & 3)) << 3)];

  const int f40 = tid, f41 = 256 + tid;
  const int kl0 = f40 >> 4, n40 = (f40 & 15) * 4;
  const int kl1 = f41 >> 4, n41 = (f41 & 15) * 4;
  const int of0 = (((kl0 >> 3) ^ (f40 & 3)) << 3) | (kl0 & 7);
  const int of1 = (((kl1 >> 3) ^ (f41 & 3)) << 3) | (kl1 & 7);
  const float* pg0 = sg + (size_t)kl0 * SIE + n0 + n40;
  const float* pg1 = sg + (size_t)kl1 * SIE + n0 + n41;
  const float* pu0 = su + (size_t)kl0 * SIE + n0 + n40;
  const float* pu1 = su + (size_t)kl1 * SIE + n0 + n41;

  const unsigned short* afr = &As[(wv * 16 + lm) * KS + x3];
  const unsigned short* bgr = &Bg[lm * KS + x3];
  const unsigned short* bur = &Bu[lm * KS + x3];

  const f32x4 zero = {0.f, 0.f, 0.f, 0.f};
  f32x4 accg[4], accu[4];
  #pragma unroll
  for (int j = 0; j < 4; ++j) { accg[j] = zero; accu[j] = zero; }

  float4 vg0 = *(const float4*)pg0, vg1 = *(const float4*)pg1;
  float4 vu0 = *(const float4*)pu0, vu1 = *(const float4*)pu1;

  for (int kb = 0; kb < HH / KB; ++kb) {
    const float4 va0 = *(const float4*)(pa + (size_t)kb * KB);
    const float4 va1 = *(const float4*)(pa + (size_t)kb * KB + 4);
    Bg[(n40+0)*KS+of0]=f2bf(vg0.x); Bg[(n40+1)*KS+of0]=f2bf(vg0.y);
    Bg[(n40+2)*KS+of0]=f2bf(vg0.z); Bg[(n40+3)*KS+of0]=f2bf(vg0.w);
    Bg[(n41+0)*KS+of1]=f2bf(vg1.x); Bg[(n41+1)*KS+of1]=f2bf(vg1.y);
    Bg[(n41+2)*KS+of1]=f2bf(vg1.z); Bg[(n41+3)*KS+of1]=f2bf(vg1.w);
    Bu[(n40+0)*KS+of0]=f2bf(vu0.x); Bu[(n40+1)*KS+of0]=f2bf(vu0.y);
    Bu[(n40+2)*KS+of0]=f2bf(vu0.z); Bu[(n40+3)*KS+of0]=f2bf(vu0.w);
    Bu[(n41+0)*KS+of1]=f2bf(vu1.x); Bu[(n41+1)*KS+of1]=f2bf(vu1.y);
    Bu[(n41+2)*KS+of1]=f2bf(vu1.z); Bu[(n41+3)*KS+of1]=f2bf(vu1.w);
    {
      short8 tv;
      tv[0]=f2bf(va0.x); tv[1]=f2bf(va0.y); tv[2]=f2bf(va0.z); tv[3]=f2bf(va0.w);
      tv[4]=f2bf(va1.x); tv[5]=f2bf(va1.y); tv[6]=f2bf(va1.z); tv[7]=f2bf(va1.w);
      *(short8*)aw = tv;
    }
    __syncthreads();
    if (kb + 1 < HH / KB) {
      const size_t k1 = (size_t)(kb + 1) * KB;
      vg0 = *(const float4*)(pg0 + k1 * SIE);
      vg1 = *(const float4*)(pg1 + k1 * SIE);
      vu0 = *(const float4*)(pu0 + k1 * SIE);
      vu1 = *(const float4*)(pu1 + k1 * SIE);
    }
    short8 a = *(const short8*)afr;
    #pragma unroll
    for (int nt = 0; nt < 4; ++nt) {
      short8 bg = *(const short8*)(bgr + nt * 16 * KS);
      short8 bu = *(const short8*)(bur + nt * 16 * KS);
      accg[nt] = __builtin_amdgcn_mfma_f32_16x16x32_bf16(a, bg, accg[nt], 0, 0, 0);
      accu[nt] = __builtin_amdgcn_mfma_f32_16x16x32_bf16(a, bu, accu[nt], 0, 0, 0);
    }
    __syncthreads();
  }

  #pragma unroll
  for (int nt = 0; nt < 4; ++nt)
    #pragma unroll
    for (int r4 = 0; r4 < 4; ++r4) {
      int row = wv * 16 + lq * 4 + r4;
      float gg = accg[nt][r4], uu = accu[nt][r4];
      float sv = gg / (1.f + expf(-gg)) * uu;
      Ps[(size_t)(m0 + row) * SIE + n0 + nt * 16 + lm] = f2bf(sv);
    }
}

// ------------------------------------------- shared down + final output
// grid 1024 = 32(mt) x 32(nc of 64)
__global__ __launch_bounds__(256) void k_sdown(
    const unsigned short* __restrict__ Ps, const float* __restrict__ sd,
    float* __restrict__ out)
{
  const int mt = blockIdx.x >> 5;   // 0..31
  const int nc = blockIdx.x & 31;   // 0..31
  const int m0 = mt * TSS, n0 = nc * NCS;

  __shared__ __align__(16) unsigned short As[TSS * KS];
  __shared__ __align__(16) unsigned short Bt[NCS * KS];

  const int tid = threadIdx.x;
  const int lane = tid & 63, wv = tid >> 6, lm = lane & 15, lq = lane >> 4;
  const int x3 = (lq ^ ((lm >> 2) & 3)) << 3;
  const int ar = tid >> 2, ag = tid & 3;

  const unsigned short* pp = Ps + (size_t)(m0 + ar) * SIE + ag * 8;
  unsigned short* aw = &As[ar * KS + ((ag ^ ((ar >> 2) & 3)) << 3)];

  const int f40 = tid, f41 = 256 + tid;
  const int kl0 = f40 >> 4, n40 = (f40 & 15) * 4;
  const int kl1 = f41 >> 4, n41 = (f41 & 15) * 4;
  const int of0 = (((kl0 >> 3) ^ (f40 & 3)) << 3) | (kl0 & 7);
  const int of1 = (((kl1 >> 3) ^ (f41 & 3)) << 3) | (kl1 & 7);
  const float* pb0 = sd + (size_t)kl0 * HH + n0 + n40;
  const float* pb1 = sd + (size_t)kl1 * HH + n0 + n41;

  const unsigned short* afr = &As[(wv * 16 + lm) * KS + x3];
  const unsigned short* btr = &Bt[lm * KS + x3];

  const f32x4 zero = {0.f, 0.f, 0.f, 0.f};
  f32x4 acc[4];
  #pragma unroll
  for (int j = 0; j < 4; ++j) acc[j] = zero;

  float4 vb0 = *(const float4*)pb0, vb1 = *(const float4*)pb1;

  for (int kb = 0; kb < SIE / KB; ++kb) {
    short8 sa = *(const short8*)(pp + (size_t)kb * KB);
    Bt[(n40+0)*KS+of0]=f2bf(vb0.x); Bt[(n40+1)*KS+of0]=f2bf(vb0.y);
    Bt[(n40+2)*KS+of0]=f2bf(vb0.z); Bt[(n40+3)*KS+of0]=f2bf(vb0.w);
    Bt[(n41+0)*KS+of1]=f2bf(vb1.x); Bt[(n41+1)*KS+of1]=f2bf(vb1.y);
    Bt[(n41+2)*KS+of1]=f2bf(vb1.z); Bt[(n41+3)*KS+of1]=f2bf(vb1.w);
    *(short8*)aw = sa;
    __syncthreads();
    if (kb + 1 < SIE / KB) {
      const size_t k1 = (size_t)(kb + 1) * KB;
      vb0 = *(const float4*)(pb0 + k1 * HH);
      vb1 = *(const float4*)(pb1 + k1 * HH);
    }
    short8 a = *(const short8*)afr;
    #pragma unroll
    for (int nt = 0; nt < 4; ++nt) {
      short8 bb = *(const short8*)(btr + nt * 16 * KS);
      acc[nt] = __builtin_amdgcn_mfma_f32_16x16x32_bf16(a, bb, acc[nt], 0, 0, 0);
    }
    __syncthreads();
  }

  #pragma unroll
  for (int nt = 0; nt < 4; ++nt)
    #pragma unroll
    for (int r4 = 0; r4 < 4; ++r4) {
      int row = wv * 16 + lq * 4 + r4;
      size_t idx = (size_t)(m0 + row) * HH + n0 + nt * 16 + lm;
      out[idx] = out[idx] + acc[nt][r4];   // experts already accumulated
    }
}

// ---------------------------------------------------------------- launch
extern "C" void kernel_launch(void* const* d_in, const int* in_sizes, int n_in,
                              void* d_out, int out_size, void* d_ws, size_t ws_size,
                              hipStream_t stream)
{
  const float* x  = (const float*)d_in[0];
  const float* rw = (const float*)d_in[1];
  const float* wg = (const float*)d_in[2];
  const float* wu = (const float*)d_in[3];
  const float* wd = (const float*)d_in[4];
  const float* sg = (const float*)d_in[5];
  const float* su = (const float*)d_in[6];
  const float* sd = (const float*)d_in[7];
  float* out = (float*)d_out;

  // workspace layout (21.6 MB total)
  char* ws = (char*)d_ws;
  int*   cnt  = (int*)ws;                                   // 1024 B
  int*   list = (int*)(ws + 1024);                          // 64*2048*4
  float* wtb  = (float*)(ws + 1024 + (size_t)NE*TT*4);      // 2048*8*4
  unsigned short* P  = (unsigned short*)(ws + 1024 + (size_t)NE*TT*4 + (size_t)TT*TOPK*4);
  unsigned short* Ps = (unsigned short*)((char*)P + (size_t)TT*TOPK*IE*2);

  hipMemsetAsync(d_out, 0, (size_t)out_size * sizeof(float), stream);
  hipMemsetAsync(cnt, 0, 1024, stream);

  k_router <<<TT/8,  256, 0, stream>>>(x, rw, cnt, list, wtb);
  k_gateup <<<4096,  512, 0, stream>>>(x, wg, wu, cnt, list, wtb, P);
  k_down   <<<16384, 512, 0, stream>>>(P, wd, cnt, list, out);
  k_sgateup<<<512,   256, 0, stream>>>(x, sg, su, Ps);
  k_sdown  <<<1024,  256, 0, stream>>>(Ps, sd, out);
}